// Round 11
// baseline (170.627 us; speedup 1.0000x reference)
//
#include <hip/hip_runtime.h>
#include <cstdint>

constexpr int NV = 32000;   // vocab / N
constexpr int NE = 256;     // embed dim
constexpr int NH = 512;     // hidden / K
constexpr int NB = 8;       // batch
constexpr int NS = 16;      // seq len
constexpr int NT = 20;      // time steps
constexpr float TH1 = 0.8f;
constexpr float TH2 = 1.0f;

typedef _Float16 f16x8 __attribute__((ext_vector_type(8)));
typedef float f32x4 __attribute__((ext_vector_type(4)));

__device__ inline float clip01(float v) { return fminf(fmaxf(v, 0.f), 1.f); }

// LDS-write drain + barrier (vmcnt deliberately left in flight: A prefetch crosses barriers)
__device__ inline void bar_lds() {
  asm volatile("s_waitcnt lgkmcnt(0)" ::: "memory");
  __builtin_amdgcn_s_barrier();
  __builtin_amdgcn_sched_barrier(0);
}

// ---------------- K1: cur1[b][s][h] = embed[x[b,s],:] . W1[h,:] + b1[h] ----------------
__global__ void k_cur1(const int* __restrict__ x, const float* __restrict__ embed,
                       const float* __restrict__ W1, const float* __restrict__ b1,
                       float* __restrict__ cur1) {
  __shared__ float e[NE];
  int bs = blockIdx.x;
  int row = x[bs];
  e[threadIdx.x] = embed[(size_t)row * NE + threadIdx.x];
  __syncthreads();
  for (int hh = 0; hh < 2; ++hh) {
    int h = threadIdx.x + hh * 256;
    const float* w = W1 + (size_t)h * NE;
    float acc = 0.f;
#pragma unroll 8
    for (int k = 0; k < NE; ++k) acc = fmaf(e[k], w[k], acc);
    cur1[(size_t)bs * NH + h] = acc + b1[h];
  }
}

// ---------------- K2: leaky recurrence -> frag-major spike matrix A2F ----------------
// A2F layout (f16 elems): [mt 40][kfi 16][rb 4][lane 64][e 8]; frag = 512 f16 = 1KB.
// Element (gs, b, h):  mt=gs>>3, kfi=h>>5, row=(gs&7)*8+b, rb=row>>4, lr=row&15,
// lane=((h&31)>>3)*16+lr, e=h&7.   (MFMA A-operand: row=lane&15, k=kfi*32+(lane>>4)*8+e)
__global__ void k_spk1(const float* __restrict__ cur1, const float* __restrict__ pbeta1,
                       _Float16* __restrict__ A2F, float* __restrict__ mem1_out) {
  int g = blockIdx.x * blockDim.x + threadIdx.x;   // 4096 = NB*NH
  int b = g >> 9, h = g & 511;
  float bc = clip01(pbeta1[0]);
  float mem = 0.f;
  const _Float16 one  = (_Float16)1.0f;
  const _Float16 zero = (_Float16)0.0f;
  const int kfi = h >> 5;
  const int lhi = (h & 31) >> 3;
  const int e   = h & 7;
  for (int s = 0; s < NS; ++s) {
    float c = cur1[((size_t)b * NS + s) * NH + h];
    for (int t = 0; t < NT; ++t) {
      float rst = (mem > TH1) ? TH1 : 0.f;
      mem = __fsub_rn(__fadd_rn(__fmul_rn(bc, mem), c), rst);    // np order
      bool spk = mem > TH1;
      int gs = s * NT + t;
      int row = (gs & 7) * 8 + b;
      int lane = lhi * 16 + (row & 15);
      size_t addr = ((((size_t)(gs >> 3) * 16 + kfi) * 4 + (row >> 4)) * 64 + lane) * 8 + e;
      A2F[addr] = spk ? one : zero;
    }
  }
  mem1_out[g] = mem;
}

// ---------------- Fused: A-from-L2 fp16 GEMM (n=128 strip) + synaptic recurrence ----------
// Grid 250 = 1 block/CU.  Block = 1024 thr = 16 waves: (kh 2) x (wm 2) x (wn 4).
// B (W2 slice, fp16, n=32 x K=256) in registers (64).  A frags loaded straight from
// L2-resident A2F via coalesced dwordx4 (no LDS staging, no vmcnt drains, 2 barriers/mt).
__global__ __launch_bounds__(1024, 4) void k_fused(
    const _Float16* __restrict__ A2F,  // frag-major spike matrix (2.62 MB, L2-resident)
    const float* __restrict__ W2,      // [32000][512] fp32
    const float* __restrict__ b2,
    const float* __restrict__ pa2, const float* __restrict__ pb2,
    float* __restrict__ out) {
  __shared__ float Cl[2][64 * 132];    // 67.6 KB, de-interleaved kh planes (2-way writes = free)

  const int tid  = threadIdx.x;
  const int lane = tid & 63;
  const int wid  = tid >> 6;           // 0..15
  const int kh   = wid >> 3;           // K half: k-chunks kh*4 .. kh*4+3
  const int wm   = (wid >> 2) & 1;     // m half (rows wm*32..+31)
  const int wn   = wid & 3;            // n quarter (cols wn*32..+31 of 128)
  const int n0   = blockIdx.x * 128;

  const int lr  = lane & 15;
  const int lk8 = (lane >> 4) * 8;
  const int cr  = (lane >> 4) * 4, cc = lane & 15;

  // ---- B prologue: 2 n-frags x 8 k-frags, fp16 (k-chunks kh*4+p, p=0..3) ----
  f16x8 bfr[2][8];
#pragma unroll
  for (int ni = 0; ni < 2; ++ni) {
    const int n = n0 + wn * 32 + ni * 16 + lr;
    const float* wp = W2 + (size_t)n * NH;
#pragma unroll
    for (int p = 0; p < 4; ++p) {
#pragma unroll
      for (int kf = 0; kf < 2; ++kf) {
        const int k0 = (kh * 4 + p) * 64 + kf * 32 + lk8;
        const float4 wa = *(const float4*)(wp + k0);
        const float4 wb = *(const float4*)(wp + k0 + 4);
        f16x8 v;
        v[0] = (_Float16)wa.x; v[1] = (_Float16)wa.y;
        v[2] = (_Float16)wa.z; v[3] = (_Float16)wa.w;
        v[4] = (_Float16)wb.x; v[5] = (_Float16)wb.y;
        v[6] = (_Float16)wb.z; v[7] = (_Float16)wb.w;
        bfr[ni][p * 2 + kf] = v;
      }
    }
  }

  const float a2  = clip01(pa2[0]);
  const float bcl = clip01(pb2[0]);
  const int vv = tid & 127;            // recurrence: owned column
  const int bb = tid >> 7;             // recurrence: owned batch
  const float b2v = b2[n0 + vv];
  float syn = 0.f, mem = 0.f;
  unsigned spkmask = 0;
  f32x4 acc[2][2] = {};

  // wave-constant A base (f16 units): frag (MT,P,kf,mb) at
  //   base + MT*32768 + P*4096 + kf*2048 + mb*512
  const _Float16* pAW = A2F + (size_t)kh * 16384 + wm * 1024 + lane * 8;

  f16x8 x0, x1, x2, x3, y0, y1, y2, y3;

#define LOADC(MT, P, S0, S1, S2, S3)                                          \
  {                                                                           \
    const _Float16* fb = pAW + (size_t)(MT) * 32768 + (P) * 4096;             \
    S0 = *(const f16x8*)(fb);          /* kf0 mb0 */                          \
    S1 = *(const f16x8*)(fb + 512);    /* kf0 mb1 */                          \
    S2 = *(const f16x8*)(fb + 2048);   /* kf1 mb0 */                          \
    S3 = *(const f16x8*)(fb + 2560);   /* kf1 mb1 */                          \
  }

#define MFMAC(P, S0, S1, S2, S3)                                              \
  {                                                                           \
    acc[0][0] = __builtin_amdgcn_mfma_f32_16x16x32_f16(S0, bfr[0][(P)*2], acc[0][0], 0, 0, 0); \
    acc[1][0] = __builtin_amdgcn_mfma_f32_16x16x32_f16(S1, bfr[0][(P)*2], acc[1][0], 0, 0, 0); \
    acc[0][1] = __builtin_amdgcn_mfma_f32_16x16x32_f16(S0, bfr[1][(P)*2], acc[0][1], 0, 0, 0); \
    acc[1][1] = __builtin_amdgcn_mfma_f32_16x16x32_f16(S1, bfr[1][(P)*2], acc[1][1], 0, 0, 0); \
    acc[0][0] = __builtin_amdgcn_mfma_f32_16x16x32_f16(S2, bfr[0][(P)*2+1], acc[0][0], 0, 0, 0); \
    acc[1][0] = __builtin_amdgcn_mfma_f32_16x16x32_f16(S3, bfr[0][(P)*2+1], acc[1][0], 0, 0, 0); \
    acc[0][1] = __builtin_amdgcn_mfma_f32_16x16x32_f16(S2, bfr[1][(P)*2+1], acc[0][1], 0, 0, 0); \
    acc[1][1] = __builtin_amdgcn_mfma_f32_16x16x32_f16(S3, bfr[1][(P)*2+1], acc[1][1], 0, 0, 0); \
  }

  LOADC(0, 0, x0, x1, x2, x3);

  for (int mt = 0; mt < 40; ++mt) {
    LOADC(mt, 1, y0, y1, y2, y3);  MFMAC(0, x0, x1, x2, x3);
    LOADC(mt, 2, x0, x1, x2, x3);  MFMAC(1, y0, y1, y2, y3);
    LOADC(mt, 3, y0, y1, y2, y3);  MFMAC(2, x0, x1, x2, x3);
    if (mt < 39) LOADC(mt + 1, 0, x0, x1, x2, x3);
    MFMAC(3, y0, y1, y2, y3);

    // ---- epilogue: each wave writes its kh plane quadrant of Cl ----
#pragma unroll
    for (int mi = 0; mi < 2; ++mi)
#pragma unroll
      for (int ni = 0; ni < 2; ++ni) {
#pragma unroll
        for (int j = 0; j < 4; ++j)
          Cl[kh][(wm * 32 + mi * 16 + cr + j) * 132 + wn * 32 + ni * 16 + cc] = acc[mi][ni][j];
        acc[mi][ni] = (f32x4){0.f, 0.f, 0.f, 0.f};
      }
    bar_lds();                                         // both kh planes visible
    // ---- 8 recurrence steps: all 1024 threads (b=tid>>7, v=tid&127) ----
#pragma unroll
    for (int st = 0; st < 8; ++st) {
      const int gs = mt * 8 + st;
      const int idx = (st * 8 + bb) * 132 + vv;
      float cur2 = __fadd_rn(__fadd_rn(Cl[0][idx], Cl[1][idx]), b2v);
      float rst = (mem > TH2) ? 1.f : 0.f;             // reset from OLD mem2
      syn = __fadd_rn(__fmul_rn(a2, syn), cur2);
      mem = __fsub_rn(__fadd_rn(__fmul_rn(bcl, mem), syn), rst);
      if (gs % 20 == 19)                               // last inner step of seq pos
        spkmask |= (mem > TH2 ? 1u : 0u) << (gs / 20);
    }
    bar_lds();                                         // Cl reads done before next epilogue
  }
#undef LOADC
#undef MFMAC

  // ---- outputs ----
#pragma unroll
  for (int s = 0; s < NS; ++s)
    out[((size_t)bb * NS + s) * NV + n0 + vv] = (spkmask >> s) & 1 ? 1.f : 0.f;
  out[(size_t)4100096 + (size_t)bb * NV + n0 + vv] = syn;   // syn2
  out[(size_t)4356096 + (size_t)bb * NV + n0 + vv] = mem;   // mem2
}

extern "C" void kernel_launch(void* const* d_in, const int* in_sizes, int n_in,
                              void* d_out, int out_size, void* d_ws, size_t ws_size,
                              hipStream_t stream) {
  const int*   x     = (const int*)d_in[0];
  const float* embed = (const float*)d_in[1];
  const float* W1    = (const float*)d_in[2];
  const float* b1    = (const float*)d_in[3];
  const float* W2    = (const float*)d_in[4];
  const float* b2    = (const float*)d_in[5];
  const float* pb1   = (const float*)d_in[6];
  const float* pa2   = (const float*)d_in[7];
  const float* pb2   = (const float*)d_in[8];
  float* out = (float*)d_out;

  char* ws = (char*)d_ws;
  float* cur1 = (float*)ws;                            // 262144 B
  _Float16* A2F = (_Float16*)(ws + 262144);            // 40*16*4*512 f16 = 2.62 MB

  hipLaunchKernelGGL(k_cur1, dim3(NB * NS), dim3(256), 0, stream, x, embed, W1, b1, cur1);
  hipLaunchKernelGGL(k_spk1, dim3(16), dim3(256), 0, stream, cur1, pb1, A2F, out + 4096000);
  hipLaunchKernelGGL(k_fused, dim3(NV / 128), dim3(1024), 0, stream,
                     A2F, W2, b2, pa2, pb2, out);
}

// Round 12
// 156.286 us; speedup vs baseline: 1.0918x; 1.0918x over previous
//
#include <hip/hip_runtime.h>
#include <cstdint>

constexpr int NV = 32000;   // vocab / N
constexpr int NE = 256;     // embed dim
constexpr int NH = 512;     // hidden / K
constexpr int NB = 8;       // batch
constexpr int NS = 16;      // seq len
constexpr int NT = 20;      // time steps
constexpr float TH1 = 0.8f;
constexpr float TH2 = 1.0f;

typedef _Float16 f16x8 __attribute__((ext_vector_type(8)));
typedef float f32x4 __attribute__((ext_vector_type(4)));

__device__ inline float clip01(float v) { return fminf(fmaxf(v, 0.f), 1.f); }

// LDS-write drain + barrier (vmcnt deliberately left in flight: A prefetch crosses barriers)
__device__ inline void bar_lds() {
  asm volatile("s_waitcnt lgkmcnt(0)" ::: "memory");
  __builtin_amdgcn_s_barrier();
  __builtin_amdgcn_sched_barrier(0);
}

// ---------------- K1: cur1[b][s][h] = embed[x[b,s],:] . W1[h,:] + b1[h] ----------------
__global__ void k_cur1(const int* __restrict__ x, const float* __restrict__ embed,
                       const float* __restrict__ W1, const float* __restrict__ b1,
                       float* __restrict__ cur1) {
  __shared__ float e[NE];
  int bs = blockIdx.x;
  int row = x[bs];
  e[threadIdx.x] = embed[(size_t)row * NE + threadIdx.x];
  __syncthreads();
  for (int hh = 0; hh < 2; ++hh) {
    int h = threadIdx.x + hh * 256;
    const float* w = W1 + (size_t)h * NE;
    float acc = 0.f;
#pragma unroll 8
    for (int k = 0; k < NE; ++k) acc = fmaf(e[k], w[k], acc);
    cur1[(size_t)bs * NH + h] = acc + b1[h];
  }
}

// ---------------- K2: leaky recurrence -> frag-major spike matrix A2F ----------------
// A2F layout (f16 elems): [mt 40][kfi 16][rb 4][lane 64][e 8]; frag = 512 f16 = 1KB.
// Element (gs, b, h):  mt=gs>>3, kfi=h>>5, row=(gs&7)*8+b, rb=row>>4, lr=row&15,
// lane=((h&31)>>3)*16+lr, e=h&7.   (MFMA A-operand: row=lane&15, k=kfi*32+(lane>>4)*8+e)
__global__ void k_spk1(const float* __restrict__ cur1, const float* __restrict__ pbeta1,
                       _Float16* __restrict__ A2F, float* __restrict__ mem1_out) {
  int g = blockIdx.x * blockDim.x + threadIdx.x;   // 4096 = NB*NH
  int b = g >> 9, h = g & 511;
  float bc = clip01(pbeta1[0]);
  float mem = 0.f;
  const _Float16 one  = (_Float16)1.0f;
  const _Float16 zero = (_Float16)0.0f;
  const int kfi = h >> 5;
  const int lhi = (h & 31) >> 3;
  const int e   = h & 7;
  for (int s = 0; s < NS; ++s) {
    float c = cur1[((size_t)b * NS + s) * NH + h];
    for (int t = 0; t < NT; ++t) {
      float rst = (mem > TH1) ? TH1 : 0.f;
      mem = __fsub_rn(__fadd_rn(__fmul_rn(bc, mem), c), rst);    // np order
      bool spk = mem > TH1;
      int gs = s * NT + t;
      int row = (gs & 7) * 8 + b;
      int lane = lhi * 16 + (row & 15);
      size_t addr = ((((size_t)(gs >> 3) * 16 + kfi) * 4 + (row >> 4)) * 64 + lane) * 8 + e;
      A2F[addr] = spk ? one : zero;
    }
  }
  mem1_out[g] = mem;
}

// ---------------- Fused: A-from-L2 fp16 GEMM (n=128 strip) + overlapped recurrence --------
// Grid 250 = 1 block/CU.  Block = 1024 thr = 16 waves: (kh 2) x (wm 2) x (wn 4).
// B (W2 slice, fp16, n=32 x K=256) in registers.  A frags straight from L2-resident A2F.
// Cl DOUBLE-buffered -> ONE barrier per mt; recurrence(mt-1) overlaps GEMM(mt).
__global__ __launch_bounds__(1024, 4) void k_fused(
    const _Float16* __restrict__ A2F,  // frag-major spike matrix (2.62 MB, L2-resident)
    const float* __restrict__ W2,      // [32000][512] fp32
    const float* __restrict__ b2,
    const float* __restrict__ pa2, const float* __restrict__ pb2,
    float* __restrict__ out) {
  __shared__ float Cl[2][2][64 * 132];  // [buf][kh plane] = 132 KB total

  const int tid  = threadIdx.x;
  const int lane = tid & 63;
  const int wid  = tid >> 6;           // 0..15
  const int kh   = wid >> 3;           // K half: k-chunks kh*4 .. kh*4+3
  const int wm   = (wid >> 2) & 1;     // m half (rows wm*32..+31)
  const int wn   = wid & 3;            // n quarter (cols wn*32..+31 of 128)
  const int n0   = blockIdx.x * 128;

  const int lr  = lane & 15;
  const int lk8 = (lane >> 4) * 8;
  const int cr  = (lane >> 4) * 4, cc = lane & 15;

  // ---- B prologue: 2 n-frags x 8 k-frags, fp16 (k-chunks kh*4+p, p=0..3) ----
  f16x8 bfr[2][8];
#pragma unroll
  for (int ni = 0; ni < 2; ++ni) {
    const int n = n0 + wn * 32 + ni * 16 + lr;
    const float* wp = W2 + (size_t)n * NH;
#pragma unroll
    for (int p = 0; p < 4; ++p) {
#pragma unroll
      for (int kf = 0; kf < 2; ++kf) {
        const int k0 = (kh * 4 + p) * 64 + kf * 32 + lk8;
        const float4 wa = *(const float4*)(wp + k0);
        const float4 wb = *(const float4*)(wp + k0 + 4);
        f16x8 v;
        v[0] = (_Float16)wa.x; v[1] = (_Float16)wa.y;
        v[2] = (_Float16)wa.z; v[3] = (_Float16)wa.w;
        v[4] = (_Float16)wb.x; v[5] = (_Float16)wb.y;
        v[6] = (_Float16)wb.z; v[7] = (_Float16)wb.w;
        bfr[ni][p * 2 + kf] = v;
      }
    }
  }

  const float a2  = clip01(pa2[0]);
  const float bcl = clip01(pb2[0]);
  const int vv = tid & 127;            // recurrence: owned column
  const int bb = tid >> 7;             // recurrence: owned batch
  const float b2v = b2[n0 + vv];
  float syn = 0.f, mem = 0.f;
  unsigned spkmask = 0;
  f32x4 acc[2][2] = {};

  // wave-constant A base (f16 units): frag (MT,P,kf,mb) at
  //   base + MT*32768 + P*4096 + kf*2048 + mb*512
  const _Float16* pAW = A2F + (size_t)kh * 16384 + wm * 1024 + lane * 8;

  f16x8 x0, x1, x2, x3, y0, y1, y2, y3;

#define LOADC(MT, P, S0, S1, S2, S3)                                          \
  {                                                                           \
    const _Float16* fb = pAW + (size_t)(MT) * 32768 + (P) * 4096;             \
    S0 = *(const f16x8*)(fb);          /* kf0 mb0 */                          \
    S1 = *(const f16x8*)(fb + 512);    /* kf0 mb1 */                          \
    S2 = *(const f16x8*)(fb + 2048);   /* kf1 mb0 */                          \
    S3 = *(const f16x8*)(fb + 2560);   /* kf1 mb1 */                          \
  }

#define MFMAC(P, S0, S1, S2, S3)                                              \
  {                                                                           \
    acc[0][0] = __builtin_amdgcn_mfma_f32_16x16x32_f16(S0, bfr[0][(P)*2], acc[0][0], 0, 0, 0); \
    acc[1][0] = __builtin_amdgcn_mfma_f32_16x16x32_f16(S1, bfr[0][(P)*2], acc[1][0], 0, 0, 0); \
    acc[0][1] = __builtin_amdgcn_mfma_f32_16x16x32_f16(S0, bfr[1][(P)*2], acc[0][1], 0, 0, 0); \
    acc[1][1] = __builtin_amdgcn_mfma_f32_16x16x32_f16(S1, bfr[1][(P)*2], acc[1][1], 0, 0, 0); \
    acc[0][0] = __builtin_amdgcn_mfma_f32_16x16x32_f16(S2, bfr[0][(P)*2+1], acc[0][0], 0, 0, 0); \
    acc[1][0] = __builtin_amdgcn_mfma_f32_16x16x32_f16(S3, bfr[0][(P)*2+1], acc[1][0], 0, 0, 0); \
    acc[0][1] = __builtin_amdgcn_mfma_f32_16x16x32_f16(S2, bfr[1][(P)*2+1], acc[0][1], 0, 0, 0); \
    acc[1][1] = __builtin_amdgcn_mfma_f32_16x16x32_f16(S3, bfr[1][(P)*2+1], acc[1][1], 0, 0, 0); \
  }

  // recurrence for tile mtq (reads Cl[mtq&1]; 16 independent ds_reads + short VALU chain)
  auto recur = [&](int mtq) {
    const float* C0 = Cl[mtq & 1][0];
    const float* C1 = Cl[mtq & 1][1];
#pragma unroll
    for (int st = 0; st < 8; ++st) {
      const int gs = mtq * 8 + st;
      const int idx = (st * 8 + bb) * 132 + vv;
      float cur2 = __fadd_rn(__fadd_rn(C0[idx], C1[idx]), b2v);
      float rst = (mem > TH2) ? 1.f : 0.f;             // reset from OLD mem2
      syn = __fadd_rn(__fmul_rn(a2, syn), cur2);
      mem = __fsub_rn(__fadd_rn(__fmul_rn(bcl, mem), syn), rst);
      if (gs % 20 == 19)                               // last inner step of seq pos
        spkmask |= (mem > TH2 ? 1u : 0u) << (gs / 20);
    }
  };

  LOADC(0, 0, x0, x1, x2, x3);

  for (int mt = 0; mt < 40; ++mt) {
    LOADC(mt, 1, y0, y1, y2, y3);
    if (mt > 0) recur(mt - 1);         // overlaps the MFMA cluster below
    __builtin_amdgcn_s_setprio(1);
    MFMAC(0, x0, x1, x2, x3);
    LOADC(mt, 2, x0, x1, x2, x3);  MFMAC(1, y0, y1, y2, y3);
    LOADC(mt, 3, y0, y1, y2, y3);  MFMAC(2, x0, x1, x2, x3);
    if (mt < 39) LOADC(mt + 1, 0, x0, x1, x2, x3);
    MFMAC(3, y0, y1, y2, y3);
    __builtin_amdgcn_s_setprio(0);

    // ---- epilogue: each wave writes its kh plane quadrant of Cl[mt&1] ----
    float* Cw = Cl[mt & 1][kh];
#pragma unroll
    for (int mi = 0; mi < 2; ++mi)
#pragma unroll
      for (int ni = 0; ni < 2; ++ni) {
#pragma unroll
        for (int j = 0; j < 4; ++j)
          Cw[(wm * 32 + mi * 16 + cr + j) * 132 + wn * 32 + ni * 16 + cc] = acc[mi][ni][j];
        acc[mi][ni] = (f32x4){0.f, 0.f, 0.f, 0.f};
      }
    bar_lds();                         // ONE rendezvous per mt
  }
  recur(39);
#undef LOADC
#undef MFMAC

  // ---- outputs ----
#pragma unroll
  for (int s = 0; s < NS; ++s)
    out[((size_t)bb * NS + s) * NV + n0 + vv] = (spkmask >> s) & 1 ? 1.f : 0.f;
  out[(size_t)4100096 + (size_t)bb * NV + n0 + vv] = syn;   // syn2
  out[(size_t)4356096 + (size_t)bb * NV + n0 + vv] = mem;   // mem2
}

extern "C" void kernel_launch(void* const* d_in, const int* in_sizes, int n_in,
                              void* d_out, int out_size, void* d_ws, size_t ws_size,
                              hipStream_t stream) {
  const int*   x     = (const int*)d_in[0];
  const float* embed = (const float*)d_in[1];
  const float* W1    = (const float*)d_in[2];
  const float* b1    = (const float*)d_in[3];
  const float* W2    = (const float*)d_in[4];
  const float* b2    = (const float*)d_in[5];
  const float* pb1   = (const float*)d_in[6];
  const float* pa2   = (const float*)d_in[7];
  const float* pb2   = (const float*)d_in[8];
  float* out = (float*)d_out;

  char* ws = (char*)d_ws;
  float* cur1 = (float*)ws;                            // 262144 B
  _Float16* A2F = (_Float16*)(ws + 262144);            // 40*16*4*512 f16 = 2.62 MB

  hipLaunchKernelGGL(k_cur1, dim3(NB * NS), dim3(256), 0, stream, x, embed, W1, b1, cur1);
  hipLaunchKernelGGL(k_spk1, dim3(16), dim3(256), 0, stream, cur1, pb1, A2F, out + 4096000);
  hipLaunchKernelGGL(k_fused, dim3(NV / 128), dim3(1024), 0, stream,
                     A2F, W2, b2, pa2, pb2, out);
}